// Round 1
// baseline (323.642 us; speedup 1.0000x reference)
//
#include <hip/hip_runtime.h>

// Sizes (fixed for this problem)
#define D_  1024
#define C_  256
#define KTILES 16   // K tiles of 64 over D=1024
#define NBP 512     // B*P

using bf16x8 = __attribute__((ext_vector_type(8))) __bf16;
using f32x4  = __attribute__((ext_vector_type(4))) float;

__device__ __forceinline__ unsigned short f2bf(float x) {
  unsigned int u = __float_as_uint(x);
  u += 0x7fffu + ((u >> 16) & 1u);
  return (unsigned short)(u >> 16);
}

// ---- prep: W_down [256][1024] f32 -> bf16, retiled [16 kt][256 ch][64]
__global__ void k_prep_wdown(const float* __restrict__ w, unsigned short* __restrict__ wdb) {
  int idx = (blockIdx.x * 256 + threadIdx.x) * 4;   // 262144 elements total
  float4 v = *(const float4*)(w + idx);
  int ch = idx >> 10;
  int d  = idx & 1023;
  int kt = d >> 6;
  int c  = d & 63;
  ushort4 o;
  o.x = f2bf(v.x); o.y = f2bf(v.y); o.z = f2bf(v.z); o.w = f2bf(v.w);
  *(ushort4*)(wdb + ((kt * 256 + ch) << 6) + c) = o;
}

// ---- prep: W_up [1024][256] f32 -> W_upT [256][1024] (LDS-tiled transpose)
__global__ void k_prep_wupT(const float* __restrict__ wup, float* __restrict__ wupT) {
  __shared__ float t[64][68];
  int bd = blockIdx.x >> 2;   // 16 d-tiles
  int bc = blockIdx.x & 3;    // 4 c-tiles
  int d0 = bd * 64, c0 = bc * 64;
  int tid = threadIdx.x;
  #pragma unroll
  for (int r = 0; r < 4; ++r) {
    int idx = r * 256 + tid;       // 1024 float4 granules: 64 rows x 16
    int dr = idx >> 4, c4 = idx & 15;
    float4 v = *(const float4*)(wup + (d0 + dr) * C_ + c0 + c4 * 4);
    t[dr][c4*4+0] = v.x; t[dr][c4*4+1] = v.y; t[dr][c4*4+2] = v.z; t[dr][c4*4+3] = v.w;
  }
  __syncthreads();
  #pragma unroll
  for (int r = 0; r < 4; ++r) {
    int idx = r * 256 + tid;
    int cr = idx >> 4, d4 = idx & 15;
    float4 v;
    v.x = t[d4*4+0][cr]; v.y = t[d4*4+1][cr]; v.z = t[d4*4+2][cr]; v.w = t[d4*4+3][cr];
    *(float4*)(wupT + (c0 + cr) * D_ + d0 + d4 * 4) = v;
  }
}

// ---- main: down-proj (bf16 MFMA) + windowed max + relu -> pooled [512][256]
__global__ __launch_bounds__(256, 2)
void k_down_pool(const float* __restrict__ hid, const unsigned short* __restrict__ wdb,
                 const float* __restrict__ bdown, float* __restrict__ pooled) {
  __shared__ unsigned short sA[64 * 64];    // 8 KB, XOR-swizzled
  __shared__ unsigned short sB[256 * 64];   // 32 KB, XOR-swizzled
  const int bp  = blockIdx.x;     // 0..511 = (b*64 + p)
  const int tid = threadIdx.x;
  const int lane = tid & 63;
  const int wv   = tid >> 6;      // wave id 0..3 -> channel group of 64
  const int l15  = lane & 15;
  const int lg   = lane >> 4;

  f32x4 acc[4][4] = {};           // [m-tile][n-tile], 16x16 frags

  const float* hbase = hid + (size_t)bp * 64 * D_;

  for (int kt = 0; kt < KTILES; ++kt) {
    // stage A: 64 rows x 64 k, fp32 -> bf16
    #pragma unroll
    for (int i = 0; i < 4; ++i) {
      int idx = i * 256 + tid;          // 1024 float4 granules
      int row = idx >> 4;
      int c4  = idx & 15;
      float4 v = *(const float4*)(hbase + row * D_ + kt * 64 + c4 * 4);
      ushort4 h;
      h.x = f2bf(v.x); h.y = f2bf(v.y); h.z = f2bf(v.z); h.w = f2bf(v.w);
      int off = row * 128 + ((c4 * 8) ^ ((row & 7) << 4));
      *(ushort4*)((char*)sA + off) = h;
    }
    // stage B: 256 ch x 64 k bf16 (contiguous 32 KB source tile)
    const unsigned short* wsrc = wdb + kt * (256 * 64);
    #pragma unroll
    for (int i = 0; i < 8; ++i) {
      int idx = i * 256 + tid;          // 2048 uint4 granules (8 bf16 each)
      int row = idx >> 3;
      int c8  = idx & 7;
      uint4 v = *(const uint4*)(wsrc + idx * 8);
      int off = row * 128 + ((c8 * 16) ^ ((row & 7) << 4));
      *(uint4*)((char*)sB + off) = v;
    }
    __syncthreads();
    #pragma unroll
    for (int ks = 0; ks < 2; ++ks) {
      bf16x8 afr[4], bfr[4];
      #pragma unroll
      for (int m = 0; m < 4; ++m) {
        int row = m * 16 + l15;
        int off = row * 128 + (((ks * 64) + lg * 16) ^ ((row & 7) << 4));
        union { uint4 u; bf16x8 v; } t;
        t.u = *(const uint4*)((const char*)sA + off);
        afr[m] = t.v;
      }
      #pragma unroll
      for (int n = 0; n < 4; ++n) {
        int row = wv * 64 + n * 16 + l15;
        int off = row * 128 + (((ks * 64) + lg * 16) ^ ((row & 7) << 4));
        union { uint4 u; bf16x8 v; } t;
        t.u = *(const uint4*)((const char*)sB + off);
        bfr[n] = t.v;
      }
      #pragma unroll
      for (int m = 0; m < 4; ++m)
        #pragma unroll
        for (int n = 0; n < 4; ++n)
          acc[m][n] = __builtin_amdgcn_mfma_f32_16x16x32_bf16(afr[m], bfr[n], acc[m][n], 0, 0, 0);
    }
    __syncthreads();
  }

  // epilogue: max over all 64 rows per column, + bias, relu
  #pragma unroll
  for (int n = 0; n < 4; ++n) {
    float vmax = -__builtin_inff();
    #pragma unroll
    for (int m = 0; m < 4; ++m)
      #pragma unroll
      for (int r = 0; r < 4; ++r)
        vmax = fmaxf(vmax, acc[m][n][r]);
    vmax = fmaxf(vmax, __shfl_xor(vmax, 16, 64));
    vmax = fmaxf(vmax, __shfl_xor(vmax, 32, 64));
    int col = wv * 64 + n * 16 + l15;
    if (lane < 16) {
      pooled[bp * C_ + col] = fmaxf(vmax + bdown[col], 0.f);
    }
  }
}

// ---- BN stats: one block, thread = channel, coalesced column reads
__global__ void k_stats(const float* __restrict__ pooled,
                        const float* __restrict__ gamma, const float* __restrict__ beta,
                        float* __restrict__ scale, float* __restrict__ shift) {
  int c = threadIdx.x;   // 0..255
  float s = 0.f, q = 0.f;
  #pragma unroll 8
  for (int i = 0; i < 512; ++i) {
    float v = pooled[i * C_ + c];
    s += v; q += v * v;
  }
  float mean = s * (1.f / 512.f);
  float var  = q * (1.f / 512.f) - mean * mean;
  float inv  = 1.f / sqrtf(var + 1e-5f);
  float sc = gamma[c] * inv;
  scale[c] = sc;
  shift[c] = beta[c] - mean * sc;
}

// ---- up-proj: [512][256] x W_upT[256][1024] -> out [512][1024]
__global__ __launch_bounds__(256)
void k_up(const float* __restrict__ pooled, const float* __restrict__ wupT,
          const float* __restrict__ scale, const float* __restrict__ shift,
          const float* __restrict__ bup, float* __restrict__ out) {
  __shared__ float sx[8][256];
  int tid = threadIdx.x;
  int dg = blockIdx.x & 3;        // 4 d-groups of 256
  int rg = blockIdx.x >> 2;       // 64 row-groups of 8
  int r0 = rg * 8;
  #pragma unroll
  for (int i = 0; i < 2; ++i) {
    int idx = i * 256 + tid;       // 512 float4 granules: 8 rows x 64
    int r = idx >> 6, c4 = idx & 63;
    float4 v  = *(const float4*)(pooled + (r0 + r) * C_ + c4 * 4);
    float4 sc = *(const float4*)(scale + c4 * 4);
    float4 sh = *(const float4*)(shift + c4 * 4);
    sx[r][c4*4+0] = v.x * sc.x + sh.x;
    sx[r][c4*4+1] = v.y * sc.y + sh.y;
    sx[r][c4*4+2] = v.z * sc.z + sh.z;
    sx[r][c4*4+3] = v.w * sc.w + sh.w;
  }
  __syncthreads();
  int d = dg * 256 + tid;
  float acc[8] = {};
  #pragma unroll 4
  for (int k = 0; k < 256; ++k) {
    float wval = wupT[k * D_ + d];
    #pragma unroll
    for (int r = 0; r < 8; ++r) acc[r] += sx[r][k] * wval;
  }
  float bb = bup[d];
  #pragma unroll
  for (int r = 0; r < 8; ++r) out[(r0 + r) * D_ + d] = acc[r] + bb;
}

extern "C" void kernel_launch(void* const* d_in, const int* in_sizes, int n_in,
                              void* d_out, int out_size, void* d_ws, size_t ws_size,
                              hipStream_t stream) {
  const float* hid   = (const float*)d_in[0];
  const float* wdown = (const float*)d_in[1];
  const float* bdown = (const float*)d_in[2];
  const float* gamma = (const float*)d_in[3];
  const float* beta  = (const float*)d_in[4];
  const float* wup   = (const float*)d_in[5];
  const float* bup   = (const float*)d_in[6];
  float* out = (float*)d_out;

  char* ws = (char*)d_ws;
  unsigned short* wdb = (unsigned short*)ws;              // 512 KB bf16 W_down (tiled)
  float* wupT   = (float*)(ws + (512 << 10));             // 1 MB
  float* pooled = (float*)(ws + (1536 << 10));            // 512 KB
  float* scale  = (float*)(ws + (2048 << 10));            // 1 KB
  float* shiftv = (float*)(ws + (2048 << 10) + 4096);     // 1 KB

  hipLaunchKernelGGL(k_prep_wdown, dim3(256), dim3(256), 0, stream, wdown, wdb);
  hipLaunchKernelGGL(k_prep_wupT,  dim3(64),  dim3(256), 0, stream, wup, wupT);
  hipLaunchKernelGGL(k_down_pool,  dim3(512), dim3(256), 0, stream, hid, wdb, bdown, pooled);
  hipLaunchKernelGGL(k_stats,      dim3(1),   dim3(256), 0, stream, pooled, gamma, beta, scale, shiftv);
  hipLaunchKernelGGL(k_up,         dim3(256), dim3(256), 0, stream, pooled, wupT, scale, shiftv, bup, out);
}

// Round 3
// 238.243 us; speedup vs baseline: 1.3585x; 1.3585x over previous
//
#include <hip/hip_runtime.h>

// Sizes (fixed): B=8, S=4096, D=1024, C=256, P=64 -> windows of 64 rows, NBP=512
#define D_  1024
#define C_  256
#define NBP 512

using bf16x8 = __attribute__((ext_vector_type(8))) __bf16;
using f32x4  = __attribute__((ext_vector_type(4))) float;

__device__ __forceinline__ unsigned short f2bf(float x) {
  unsigned int u = __float_as_uint(x);
  u += 0x7fffu + ((u >> 16) & 1u);
  return (unsigned short)(u >> 16);
}

typedef __attribute__((address_space(1))) const void* gas_t;
typedef __attribute__((address_space(3))) void* las_t;
__device__ __forceinline__ void dma16(const void* g, void* l) {
  __builtin_amdgcn_global_load_lds((gas_t)g, (las_t)l, 16, 0, 0);
}

// ---- fused prep:
//  blocks [0,256):   W_down f32 -> bf16, tiled [16 kt][256 ch][128B], PRE-SWIZZLED
//                    (byte = kt*32768 + ch*128 + ((2k) ^ ((ch&7)<<4)))
//  blocks [256,320): W_up [1024][256] -> W_upT [256][1024] (LDS transpose)
//  block  320:       zero BN accumulators
__global__ void k_prep(const float* __restrict__ wdown, const float* __restrict__ wup,
                       unsigned short* __restrict__ wdb, float* __restrict__ wupT,
                       float* __restrict__ gsum, float* __restrict__ gsq) {
  int bid = blockIdx.x, tid = threadIdx.x;
  if (bid < 256) {
    int idx = (bid * 256 + tid) * 4;            // 262144 elements
    float4 v = *(const float4*)(wdown + idx);
    int ch = idx >> 10;
    int d  = idx & 1023;
    int kt = d >> 6;
    int c  = d & 63;                             // multiple of 4
    ushort4 o;
    o.x = f2bf(v.x); o.y = f2bf(v.y); o.z = f2bf(v.z); o.w = f2bf(v.w);
    int dstbyte = kt * 32768 + ch * 128 + ((c * 2) ^ ((ch & 7) << 4));
    *(ushort4*)((char*)wdb + dstbyte) = o;
  } else if (bid < 320) {
    __shared__ float t[64][68];
    int b2 = bid - 256;
    int d0 = (b2 >> 2) * 64, c0 = (b2 & 3) * 64;
    #pragma unroll
    for (int r = 0; r < 4; ++r) {
      int idx = r * 256 + tid;
      int dr = idx >> 4, c4 = idx & 15;
      float4 v = *(const float4*)(wup + (d0 + dr) * C_ + c0 + c4 * 4);
      t[dr][c4*4+0] = v.x; t[dr][c4*4+1] = v.y; t[dr][c4*4+2] = v.z; t[dr][c4*4+3] = v.w;
    }
    __syncthreads();
    #pragma unroll
    for (int r = 0; r < 4; ++r) {
      int idx = r * 256 + tid;
      int cr = idx >> 4, d4 = idx & 15;
      float4 v;
      v.x = t[d4*4+0][cr]; v.y = t[d4*4+1][cr]; v.z = t[d4*4+2][cr]; v.w = t[d4*4+3][cr];
      *(float4*)(wupT + (c0 + cr) * D_ + d0 + d4 * 4) = v;
    }
  } else {
    gsum[tid] = 0.f;
    gsq[tid]  = 0.f;
  }
}

// ---- main: down-proj (bf16 MFMA, double-buffered pipeline) + window-max + relu
//      + BN partial sums via atomics
__global__ __launch_bounds__(256, 2)
void k_down_pool(const float* __restrict__ hid, const unsigned short* __restrict__ wdb,
                 const float* __restrict__ bdown, float* __restrict__ pooled,
                 float* __restrict__ gsum, float* __restrict__ gsq) {
  // distinct buffers so parity-unrolled loop has provably-disjoint LDS objects
  __shared__ unsigned short sA0[4096], sA1[4096];     // 8 KB each (64 rows x 128B, swizzled)
  __shared__ unsigned short sB0[16384], sB1[16384];   // 32 KB each (256 ch x 128B, swizzled)
  const int bp   = blockIdx.x;      // window id (b*64+p)
  const int tid  = threadIdx.x;
  const int lane = tid & 63;
  const int wv   = tid >> 6;        // wave -> 64-channel group
  const int l15  = lane & 15;
  const int lg   = lane >> 4;

  const float* hbase = hid + (size_t)bp * 64 * D_;

  f32x4 acc[4][4] = {};
  float4 areg[4];

  // B tile DMA: 32 KB, linear LDS dest (source pre-swizzled in k_prep)
  auto issueB = [&](unsigned short* sB, int kt) {
    const char* src = (const char*)wdb + kt * 32768;
    #pragma unroll
    for (int i = 0; i < 8; ++i) {
      int off = (i * 4 + wv) * 1024 + lane * 16;   // wave-uniform base + lane*16
      dma16(src + off, (char*)sB + off);
    }
  };
  // A tile: issue global fp32 loads into regs
  auto loadA = [&](int kt) {
    #pragma unroll
    for (int i = 0; i < 4; ++i) {
      int idx = i * 256 + tid;
      int row = idx >> 4, c4 = idx & 15;
      areg[i] = *(const float4*)(hbase + row * D_ + kt * 64 + c4 * 4);
    }
  };
  // A tile: convert + swizzled LDS write
  auto writeA = [&](unsigned short* sA) {
    #pragma unroll
    for (int i = 0; i < 4; ++i) {
      int idx = i * 256 + tid;
      int row = idx >> 4, c4 = idx & 15;
      ushort4 h;
      h.x = f2bf(areg[i].x); h.y = f2bf(areg[i].y); h.z = f2bf(areg[i].z); h.w = f2bf(areg[i].w);
      int off = row * 128 + ((c4 * 8) ^ ((row & 7) << 4));
      *(ushort4*)((char*)sA + off) = h;
    }
  };
  auto compute = [&](const unsigned short* sA, const unsigned short* sB) {
    #pragma unroll
    for (int ks = 0; ks < 2; ++ks) {
      bf16x8 afr[4], bfr[4];
      #pragma unroll
      for (int m = 0; m < 4; ++m) {
        int row = m * 16 + l15;
        int off = row * 128 + ((ks * 64 + lg * 16) ^ ((row & 7) << 4));
        union { uint4 u; bf16x8 v; } t;
        t.u = *(const uint4*)((const char*)sA + off);
        afr[m] = t.v;
      }
      #pragma unroll
      for (int n = 0; n < 4; ++n) {
        int row = wv * 64 + n * 16 + l15;
        int off = row * 128 + ((ks * 64 + lg * 16) ^ ((row & 7) << 4));
        union { uint4 u; bf16x8 v; } t;
        t.u = *(const uint4*)((const char*)sB + off);
        bfr[n] = t.v;
      }
      #pragma unroll
      for (int m = 0; m < 4; ++m)
        #pragma unroll
        for (int n = 0; n < 4; ++n)
          acc[m][n] = __builtin_amdgcn_mfma_f32_16x16x32_bf16(afr[m], bfr[n], acc[m][n], 0, 0, 0);
    }
  };

  // prologue: stage tile 0 into buffer 0
  issueB(sB0, 0);
  loadA(0);
  writeA(sA0);           // compiler inserts vmcnt wait for areg deps
  __syncthreads();       // drains DMA (vmcnt 0) + makes ds_writes visible

  #pragma unroll 1
  for (int kt = 0; kt < 16; kt += 2) {
    // even phase: compute buf0, stage kt+1 into buf1
    issueB(sB1, kt + 1);
    loadA(kt + 1);
    compute(sA0, sB0);
    writeA(sA1);
    __syncthreads();
    // odd phase: compute buf1, stage kt+2 into buf0
    if (kt + 2 < 16) {
      issueB(sB0, kt + 2);
      loadA(kt + 2);
    }
    compute(sA1, sB1);
    if (kt + 2 < 16) writeA(sA0);
    __syncthreads();
  }

  // epilogue: max over 64 rows per channel, + bias, relu, BN partial sums
  #pragma unroll
  for (int n = 0; n < 4; ++n) {
    float vmax = -__builtin_inff();
    #pragma unroll
    for (int m = 0; m < 4; ++m)
      #pragma unroll
      for (int r = 0; r < 4; ++r)
        vmax = fmaxf(vmax, acc[m][n][r]);
    vmax = fmaxf(vmax, __shfl_xor(vmax, 16, 64));
    vmax = fmaxf(vmax, __shfl_xor(vmax, 32, 64));
    int col = wv * 64 + n * 16 + l15;
    if (lane < 16) {
      float pv = fmaxf(vmax + bdown[col], 0.f);
      pooled[bp * C_ + col] = pv;
      atomicAdd(&gsum[col], pv);
      atomicAdd(&gsq[col],  pv * pv);
    }
  }
}

// ---- BN finalize: scale/shift per channel (1 block)
__global__ void k_stats_final(const float* __restrict__ gsum, const float* __restrict__ gsq,
                              const float* __restrict__ gamma, const float* __restrict__ beta,
                              float* __restrict__ scale, float* __restrict__ shift) {
  int c = threadIdx.x;
  float mean = gsum[c] * (1.f / 512.f);
  float var  = gsq[c] * (1.f / 512.f) - mean * mean;
  float inv  = 1.f / sqrtf(var + 1e-5f);
  float sc = gamma[c] * inv;
  scale[c] = sc;
  shift[c] = beta[c] - mean * sc;
}

// ---- up-proj: 256 blocks x (2 rows x 1024 d); thread owns 4 consecutive d
__global__ __launch_bounds__(256)
void k_up(const float* __restrict__ pooled, const float* __restrict__ wupT,
          const float* __restrict__ scale, const float* __restrict__ shift,
          const float* __restrict__ bup, float* __restrict__ out) {
  __shared__ float sx0[256], sx1[256];
  int tid = threadIdx.x;
  int r0 = blockIdx.x * 2;
  float sc = scale[tid], sh = shift[tid];
  sx0[tid] = pooled[r0 * C_ + tid] * sc + sh;
  sx1[tid] = pooled[(r0 + 1) * C_ + tid] * sc + sh;
  __syncthreads();
  int d4 = tid * 4;
  float a0=0,a1=0,a2=0,a3=0,b0=0,b1=0,b2=0,b3=0;
  #pragma unroll 8
  for (int k = 0; k < 256; ++k) {
    float4 w = *(const float4*)(wupT + (size_t)k * D_ + d4);
    float x0 = sx0[k], x1 = sx1[k];
    a0 += w.x * x0; a1 += w.y * x0; a2 += w.z * x0; a3 += w.w * x0;
    b0 += w.x * x1; b1 += w.y * x1; b2 += w.z * x1; b3 += w.w * x1;
  }
  float4 bb = *(const float4*)(bup + d4);
  float4 o0 = {a0 + bb.x, a1 + bb.y, a2 + bb.z, a3 + bb.w};
  float4 o1 = {b0 + bb.x, b1 + bb.y, b2 + bb.z, b3 + bb.w};
  *(float4*)(out + (size_t)r0 * D_ + d4) = o0;
  *(float4*)(out + (size_t)(r0 + 1) * D_ + d4) = o1;
}

extern "C" void kernel_launch(void* const* d_in, const int* in_sizes, int n_in,
                              void* d_out, int out_size, void* d_ws, size_t ws_size,
                              hipStream_t stream) {
  const float* hid   = (const float*)d_in[0];
  const float* wdown = (const float*)d_in[1];
  const float* bdown = (const float*)d_in[2];
  const float* gamma = (const float*)d_in[3];
  const float* beta  = (const float*)d_in[4];
  const float* wup   = (const float*)d_in[5];
  const float* bup   = (const float*)d_in[6];
  float* out = (float*)d_out;

  char* ws = (char*)d_ws;
  unsigned short* wdb = (unsigned short*)ws;               // 512 KB (pre-swizzled bf16)
  float* wupT   = (float*)(ws + (512 << 10));              // 1 MB
  float* pooled = (float*)(ws + (1536 << 10));             // 512 KB
  float* gsum   = (float*)(ws + (2048 << 10));             // 1 KB
  float* gsq    = (float*)(ws + (2048 << 10) + 1024);      // 1 KB
  float* scale  = (float*)(ws + (2048 << 10) + 2048);      // 1 KB
  float* shiftv = (float*)(ws + (2048 << 10) + 3072);      // 1 KB

  hipLaunchKernelGGL(k_prep,        dim3(321), dim3(256), 0, stream, wdown, wup, wdb, wupT, gsum, gsq);
  hipLaunchKernelGGL(k_down_pool,   dim3(512), dim3(256), 0, stream, hid, wdb, bdown, pooled, gsum, gsq);
  hipLaunchKernelGGL(k_stats_final, dim3(1),   dim3(256), 0, stream, gsum, gsq, gamma, beta, scale, shiftv);
  hipLaunchKernelGGL(k_up,          dim3(256), dim3(256), 0, stream, pooled, wupT, scale, shiftv, bup, out);
}